// Round 12
// baseline (240.657 us; speedup 1.0000x reference)
//
#include <hip/hip_runtime.h>
#include <float.h>
#include <math.h>

// Problem constants (reference: x shape (2,1024,32000) fp32, dim=-1, alpha=1.5)
// All math in v-space (v = 2z = x). 0.5 is a power of two: z = 0.5v exact,
// tau = 0.5u exact, and p = max(z-tau,0)^2/sum_z == max(v-u,0)^2/sum_v (the
// 0.25 cancels exactly). No scale multiply anywhere.
#define D_DIM   32000
#define NT      256                         // 4 waves -> 8 blocks/CU
#define CHUNKS  (D_DIM / 4)                 // 8000 float4 chunks per row
#define KITER   ((CHUNKS + NT - 1) / NT)    // 32 chunks per thread
#define NWAVES  (NT / 64)                   // 4
#define CAPW    1024                        // per-wave pool (exact active ~150)

typedef float f32x4 __attribute__((ext_vector_type(4)));
typedef unsigned long long ull;

__device__ __forceinline__ float waveReduceSum(float v) {
#pragma unroll
    for (int m = 32; m >= 1; m >>= 1) v += __shfl_xor(v, m, 64);
    return v;
}

__device__ __forceinline__ float waveReduceMax(float v) {
#pragma unroll
    for (int m = 32; m >= 1; m >>= 1) v = fmaxf(v, __shfl_xor(v, m, 64));
    return v;
}

// Bit-level finite scrub: maps NaN and +/-inf to -FLT_MAX. Integer-domain so
// -ffinite-math-only cannot fold it away.
__device__ __forceinline__ float scrub_finite(float v) {
    const unsigned u = __float_as_uint(v);
    if ((u & 0x7f800000u) == 0x7f800000u) return -FLT_MAX;
    return v;
}

__device__ __forceinline__ float4 ldg4(const float4* __restrict__ p, int c) {
    if (c < CHUNKS) return p[c];
    float4 r; r.x = r.y = r.z = r.w = -FLT_MAX;   // pad stays hugely negative
    return r;
}

// Fused kernel, R12 structure (R11 lesson: pass-1 with running-max admission
// ran at 2.3 TB/s = 2.7x the read floor; the serial per-group chain
// load->max->reduce->ballot->append was the throttle, and the compiler sank
// the prefetch (VGPR=28). Fix: split pass-1 into two simple passes, using the
// PROVEN fact (R7/R10: FETCH ~= 1x input) that re-reads hit L3 for free.)
//  A : pure max stream - 4 independent fmax accumulators, zero LDS/shuffle/
//      ballot work in the loop. The exact loop shape that runs at BW floor.
//  B : re-read from L3; admission at the EXACT threshold max-2 (one ballot+
//      rank per component; no running max, no evictions). Pool = exact active
//      set. S2/S1 at u_lo0 accumulated on the fly (Newton's 1st scan free).
//  solve : wave-0 warm-started Newton on f(u)=sum max(v-u,0)^2 (convex
//      decreasing -> monotone from below, ~5-7 scans). Waves 1-3 wait.
//  epilog : third touch (L3) with nt-load (last use, evict-first) ->
//      log(max(v-u,0)^2 * inv_sv), nt-store. Verified numeric path.
__global__ __launch_bounds__(NT, 8)
void entmax_log_fused(const float* __restrict__ x, float* __restrict__ out, int rows)
{
    const int row = blockIdx.x;
    if (row >= rows) return;
    const size_t base = (size_t)row * D_DIM;
    const float4* __restrict__ xr4 = reinterpret_cast<const float4*>(x + base);
    float* __restrict__ orow = out + base;

    __shared__ __align__(16) float s_pool[NWAVES * CAPW];   // 16 KB
    __shared__ float s_red[NWAVES];
    __shared__ float s_S2[NWAVES];
    __shared__ float s_S1[NWAVES];
    __shared__ int   s_cnt[NWAVES];
    __shared__ int   s_flag;
    __shared__ float2 s_ts;

    const int lane = threadIdx.x & 63;
    const int wv   = threadIdx.x >> 6;
    float* __restrict__ wpool = s_pool + wv * CAPW;
    const ull lmask = (1ull << lane) - 1ull;

    if (threadIdx.x == 0) s_flag = 0;

    // ---- phase A: pure max stream (no dependencies between iterations) ----
    float m0 = -FLT_MAX, m1 = -FLT_MAX, m2 = -FLT_MAX, m3 = -FLT_MAX;
    for (int k = 0; k < KITER; ++k) {
        const float4 v = ldg4(xr4, threadIdx.x + k * NT);
        m0 = fmaxf(m0, v.x); m1 = fmaxf(m1, v.y);
        m2 = fmaxf(m2, v.z); m3 = fmaxf(m3, v.w);
    }
    float m = fmaxf(fmaxf(m0, m1), fmaxf(m2, m3));
    m = waveReduceMax(m);
    if (lane == 0) s_red[wv] = m;
    __syncthreads();                     // also publishes s_flag = 0
    const float max_val = fmaxf(fmaxf(s_red[0], s_red[1]), fmaxf(s_red[2], s_red[3]));

    // v-space bounds: u = 2*tau.
    const float u_lo0 = max_val - 2.0f;
    const float u_hi  = max_val - 0.011180339887498949f;   // 2*(1/32000)^0.5

    // ---- phase B: exact-threshold admission from L3 + fused S2/S1 @ u_lo0 ----
    // Pool = exactly {v > max-2} (strict: v == max-2 has t = 0, excluded is
    // exact). Deterministic order (k, component, lane). Elements outside the
    // pool contribute exactly 0 to every f(u) at u >= max-2.
    {
        int n = 0;
        float a2 = 0.0f, a1 = 0.0f;
        for (int k = 0; k < KITER; ++k) {
            const float4 v = ldg4(xr4, threadIdx.x + k * NT);
#define ADMIT(zz)                                                          \
            do {                                                           \
                const float z_ = (zz);                                     \
                const ull mk = __ballot(z_ > u_lo0);                       \
                if (mk) {                                                  \
                    if (z_ > u_lo0) {                                      \
                        const int pos = n + __popcll(mk & lmask);          \
                        if (pos < CAPW) wpool[pos] = z_;                   \
                        const float t = z_ - u_lo0;                        \
                        a2 = fmaf(t, t, a2); a1 += t;                      \
                    }                                                      \
                    n += __popcll(mk);                                     \
                }                                                          \
            } while (0)
            ADMIT(v.x); ADMIT(v.y); ADMIT(v.z); ADMIT(v.w);
#undef ADMIT
        }
        a2 = waveReduceSum(a2);
        a1 = waveReduceSum(a1);
        if (lane == 0) {
            s_cnt[wv] = n;
            s_S2[wv] = a2;
            s_S1[wv] = a1;
            if (n > CAPW) s_flag = 1;   // tie-degenerate rows only
        }
    }
    __syncthreads();
    const int flag = s_flag;

    if (!flag) {
        // ---- wave-0-only warm-started Newton over all 4 pools ----
        // g(u) = f(u) - 4, f convex decreasing: tangent steps from u_lo0
        // converge monotonically from below (fp overshoot ~1 ulp). The max
        // element contributes exactly 4 at u_lo0 so g(u_lo0) >= 0; the
        // all-equal row roots exactly at u_hi, so the clamp is exact.
        if (wv == 0) {
            const int n0 = s_cnt[0], n1 = s_cnt[1], n2 = s_cnt[2], n3 = s_cnt[3];
            float u   = u_lo0;
            float s_v = s_S2[0] + s_S2[1] + s_S2[2] + s_S2[3];   // f(u_lo0)
            float g   = s_v - 4.0f;
            float S1  = s_S1[0] + s_S1[1] + s_S1[2] + s_S1[3];

            for (int it = 0; it < 24 && g > 0.0f; ++it) {
                const float u_new = fminf(u + g / (2.0f * S1), u_hi);
                if (u_new == u) break;      // fixpoint: root to fp32 precision
                u = u_new;
                float S2 = 0.0f; S1 = 0.0f;
                {
                    const float* __restrict__ pp0 = s_pool;
                    for (int i = lane; i < n0; i += 64) {
                        const float t = fmaxf(pp0[i] - u, 0.0f);
                        S2 = fmaf(t, t, S2); S1 += t;
                    }
                    const float* __restrict__ pp1 = s_pool + CAPW;
                    for (int i = lane; i < n1; i += 64) {
                        const float t = fmaxf(pp1[i] - u, 0.0f);
                        S2 = fmaf(t, t, S2); S1 += t;
                    }
                    const float* __restrict__ pp2 = s_pool + 2 * CAPW;
                    for (int i = lane; i < n2; i += 64) {
                        const float t = fmaxf(pp2[i] - u, 0.0f);
                        S2 = fmaf(t, t, S2); S1 += t;
                    }
                    const float* __restrict__ pp3 = s_pool + 3 * CAPW;
                    for (int i = lane; i < n3; i += 64) {
                        const float t = fmaxf(pp3[i] - u, 0.0f);
                        S2 = fmaf(t, t, S2); S1 += t;
                    }
                }
                S2 = waveReduceSum(S2);
                S1 = waveReduceSum(S1);
                s_v = S2;                   // f at the CURRENT u
                g = S2 - 4.0f;              // g <= 0 -> at/past root (~1 ulp)
            }
            if (lane == 0) { s_ts.x = u; s_ts.y = s_v; }
        }
        __syncthreads();   // solver result published
    } else {
        // ---- fallback (tie-degenerate rows only): streaming bisection ----
        float u_lo = u_lo0;
        float acc = 0.0f;
        for (int k = 0; k < KITER; ++k) {
            const int c = threadIdx.x + k * NT;
            if (c < CHUNKS) {
                const float4 v = xr4[c];
                float t;
                t = fmaxf(v.x - u_lo, 0.0f); acc = fmaf(t, t, acc);
                t = fmaxf(v.y - u_lo, 0.0f); acc = fmaf(t, t, acc);
                t = fmaxf(v.z - u_lo, 0.0f); acc = fmaf(t, t, acc);
                t = fmaxf(v.w - u_lo, 0.0f); acc = fmaf(t, t, acc);
            }
        }
        acc = waveReduceSum(acc);
        if (lane == 0) s_red[wv] = acc;
        __syncthreads();
        const float f_lo = (s_red[0] + s_red[1] + s_red[2] + s_red[3]) - 4.0f;
        __syncthreads();

        float dm = u_hi - u_lo;
        float u_m = u_lo;
        float s_v = 4.0f;
        for (int it = 0; it < 100; ++it) {
            dm *= 0.5f;
            u_m = u_lo + dm;
            const bool fixed = (u_m == u_lo);
            float a = 0.0f;
            for (int k = 0; k < KITER; ++k) {
                const int c = threadIdx.x + k * NT;
                if (c < CHUNKS) {
                    const float4 v = xr4[c];
                    float t;
                    t = fmaxf(v.x - u_m, 0.0f); a = fmaf(t, t, a);
                    t = fmaxf(v.y - u_m, 0.0f); a = fmaf(t, t, a);
                    t = fmaxf(v.z - u_m, 0.0f); a = fmaf(t, t, a);
                    t = fmaxf(v.w - u_m, 0.0f); a = fmaf(t, t, a);
                }
            }
            a = waveReduceSum(a);
            if (lane == 0) s_red[wv] = a;
            __syncthreads();
            const float s = s_red[0] + s_red[1] + s_red[2] + s_red[3];
            __syncthreads();
            s_v = s;
            if ((s - 4.0f) * f_lo >= 0.0f) u_lo = u_m;
            if (fixed) break;
        }
        if (threadIdx.x == 0) { s_ts.x = u_m; s_ts.y = s_v; }
        __syncthreads();
    }

    // ---- epilogue: nt-load re-read (L3-hot, last use) -> log, nt-store ----
    // p = max(v-u,0)^2 * inv_sv is EXACTLY the z-space normalized probability.
    // Floor before log (DAZ-safe), bit-scrub residual inf/NaN.
    const float u_m = s_ts.x;
    const float inv_sv = 1.0f / s_ts.y;
    const f32x4* __restrict__ xv4 = reinterpret_cast<const f32x4*>(x + base);
    for (int k = 0; k < KITER; ++k) {
        const int c = threadIdx.x + k * NT;
        if (c < CHUNKS) {
            const f32x4 v = __builtin_nontemporal_load(xv4 + c);
            f32x4 o;
            {
                const float t = fmaxf(v.x - u_m, 0.0f);
                o.x = scrub_finite(__logf(fmaxf(t * t, 1e-35f) * inv_sv));
            }
            {
                const float t = fmaxf(v.y - u_m, 0.0f);
                o.y = scrub_finite(__logf(fmaxf(t * t, 1e-35f) * inv_sv));
            }
            {
                const float t = fmaxf(v.z - u_m, 0.0f);
                o.z = scrub_finite(__logf(fmaxf(t * t, 1e-35f) * inv_sv));
            }
            {
                const float t = fmaxf(v.w - u_m, 0.0f);
                o.w = scrub_finite(__logf(fmaxf(t * t, 1e-35f) * inv_sv));
            }
            __builtin_nontemporal_store(o, reinterpret_cast<f32x4*>(orow) + c);
        }
    }
}

extern "C" void kernel_launch(void* const* d_in, const int* in_sizes, int n_in,
                              void* d_out, int out_size, void* d_ws, size_t ws_size,
                              hipStream_t stream) {
    const float* x = (const float*)d_in[0];
    float* out = (float*)d_out;
    const int rows = in_sizes[0] / D_DIM;
    entmax_log_fused<<<dim3(rows), dim3(NT), 0, stream>>>(x, out, rows);
}

// Round 13
// 130.603 us; speedup vs baseline: 1.8427x; 1.8427x over previous
//
#include <hip/hip_runtime.h>
#include <float.h>
#include <math.h>

// Problem constants (reference: x shape (2,1024,32000) fp32, dim=-1, alpha=1.5)
// All math in v-space (v = 2z = x). 0.5 is a power of two: z = 0.5v exact,
// tau = 0.5u exact, p = max(z-tau,0)^2/sum_z == max(v-u,0)^2/sum_v (the 0.25
// cancels exactly). No scale multiply anywhere.
#define D_DIM   32000
#define NT      256                         // 4 waves -> 8 blocks/CU
#define CHUNKS  (D_DIM / 4)                 // 8000 float4 chunks per row
#define KITER   ((CHUNKS + NT - 1) / NT)    // 32 chunks per thread
#define NG4     (KITER / 4)                 // 8 four-chunk groups (16 elems each)
#define NWAVES  (NT / 64)                   // 4
#define CAPW    1200                        // per-wave pool capacity (4800 B)

typedef float f32x4 __attribute__((ext_vector_type(4)));
typedef unsigned long long ull;

__device__ __forceinline__ float waveReduceSum(float v) {
#pragma unroll
    for (int m = 32; m >= 1; m >>= 1) v += __shfl_xor(v, m, 64);
    return v;
}

__device__ __forceinline__ float waveReduceMax(float v) {
#pragma unroll
    for (int m = 32; m >= 1; m >>= 1) v = fmaxf(v, __shfl_xor(v, m, 64));
    return v;
}

// Bit-level finite scrub: maps NaN and +/-inf to -FLT_MAX. Integer-domain so
// -ffinite-math-only cannot fold it away.
__device__ __forceinline__ float scrub_finite(float v) {
    const unsigned u = __float_as_uint(v);
    if ((u & 0x7f800000u) == 0x7f800000u) return -FLT_MAX;
    return v;
}

__device__ __forceinline__ float4 ldg4(const float4* __restrict__ p, int c) {
    if (c < CHUNKS) return p[c];
    float4 r; r.x = r.y = r.z = r.w = -FLT_MAX;   // pad stays hugely negative
    return r;
}

// One 16-element group of pass-1 (identical arithmetic/order to the verified
// R10 kernel; factored out so the ping-pong loop can call it on either buffer).
__device__ __forceinline__ void proc_group(
    const float4 (&buf)[4], int gidx,
    float& runL, float& waveM, float& pendR,
    int& n, bool& ovf,
    float* __restrict__ wpool, int lane, ull lmask)
{
    float z[16];
#pragma unroll
    for (int j = 0; j < 4; ++j) {
        z[4 * j + 0] = buf[j].x; z[4 * j + 1] = buf[j].y;
        z[4 * j + 2] = buf[j].z; z[4 * j + 3] = buf[j].w;
    }
    float cm = z[0];
#pragma unroll
    for (int i = 1; i < 16; ++i) cm = fmaxf(cm, z[i]);
    runL = fmaxf(runL, cm);
    if ((gidx & 1) == 0) {                // every 8 chunks (R10 cadence)
        waveM = fmaxf(waveM, pendR);      // consume reduce from 2 groups ago
        pendR = waveReduceMax(runL);      // launch new; 2 group-times to land
    }

    float thrL = fmaxf(runL, waveM) - 2.0f;   // per-lane lower bound of max-2
    ull msk[16];
    int tot = 0;
#pragma unroll
    for (int j = 0; j < 16; ++j) {
        msk[j] = __ballot(z[j] > thrL);
        tot += __popcll(msk[j]);
    }
    if (tot) {
        if (n + tot > CAPW) {
            // fresh uniform wave max; evict dead entries (<= wfresh-2).
            const float wfresh = waveReduceMax(runL);
            waveM = fmaxf(waveM, wfresh);
            const float thrW = wfresh - 2.0f;
            int nn = 0;
            for (int i = 0; i < n; i += 64) {
                const float v = (i + lane < n) ? wpool[i + lane] : -FLT_MAX;
                const ull km = __ballot(v > thrW);
                const int r = __popcll(km & lmask);
                if (v > thrW) wpool[nn + r] = v;   // dest <= src: in-place safe
                nn += __popcll(km);
            }
            n = nn;
            // re-admit this group against the tightened threshold
            thrL = fmaxf(runL, waveM) - 2.0f;
            tot = 0;
#pragma unroll
            for (int j = 0; j < 16; ++j) {
                msk[j] = __ballot(z[j] > thrL);
                tot += __popcll(msk[j]);
            }
        }
        if (n + tot > CAPW) {
            ovf = true;          // adversarial/degenerate rows only
        } else {
#pragma unroll
            for (int j = 0; j < 16; ++j) {
                if (z[j] > thrL) {
                    const int r = __popcll(msk[j] & lmask);
                    wpool[n + r] = z[j];
                }
                n += __popcll(msk[j]);
            }
        }
    }
}

// Fused kernel (R10 skeleton = verified 127.6us best):
//  pass 1 : stream row raw; lag-pipelined wave max admission into per-wave
//           LDS pools. R13: PING-PONG prefetch with sched_barrier(0) pinning
//           (R11 showed VGPR=28 -> compiler had sunk the prefetch; this keeps
//           4 loads in flight while the other buffer is processed; identical
//           arithmetic order).
//  solve  : final eviction at max-2, wave-0 Newton on f(u)=sum max(v-u,0)^2
//           (convex decreasing: monotone from below, ~6-8 scans).
//  epilog : nt-load re-read (L3-hot, last use) -> log(t^2*inv_sv), nt-store.
__global__ __launch_bounds__(NT, 8)
void entmax_log_fused(const float* __restrict__ x, float* __restrict__ out, int rows)
{
    const int row = blockIdx.x;
    if (row >= rows) return;
    const size_t base = (size_t)row * D_DIM;
    const float4* __restrict__ xr4 = reinterpret_cast<const float4*>(x + base);
    float* __restrict__ orow = out + base;

    __shared__ __align__(16) float s_pool[NWAVES * CAPW];   // 19200 B
    __shared__ float s_red[NWAVES];
    __shared__ int   s_cnt[NWAVES];
    __shared__ int   s_flag;
    __shared__ float2 s_ts;

    const int lane = threadIdx.x & 63;
    const int wv   = threadIdx.x >> 6;
    float* __restrict__ wpool = s_pool + wv * CAPW;
    const ull lmask = (1ull << lane) - 1ull;

    if (threadIdx.x == 0) s_flag = 0;
    __syncthreads();

    // ---- pass 1: ping-pong prefetched stream + pooled admission ----
    float runL  = -FLT_MAX;   // per-lane running max (raw v)
    float waveM = -FLT_MAX;   // wave max through 2 groups ago (uniform)
    float pendR = -FLT_MAX;   // in-flight reduce result
    int n = 0;                // wave-uniform pool count
    bool ovf = false;

    float4 bufA[4], bufB[4];
#pragma unroll
    for (int j = 0; j < 4; ++j) bufA[j] = ldg4(xr4, threadIdx.x + j * NT);

    for (int g = 0; g < NG4; g += 2) {
        // issue loads for group g+1 into bufB, pin them above the processing
#pragma unroll
        for (int j = 0; j < 4; ++j)
            bufB[j] = ldg4(xr4, threadIdx.x + ((g + 1) * 4 + j) * NT);
        __builtin_amdgcn_sched_barrier(0);
        proc_group(bufA, g, runL, waveM, pendR, n, ovf, wpool, lane, lmask);

        // issue loads for group g+2 into bufA (OOB-guarded past the end)
#pragma unroll
        for (int j = 0; j < 4; ++j)
            bufA[j] = ldg4(xr4, threadIdx.x + ((g + 2) * 4 + j) * NT);
        __builtin_amdgcn_sched_barrier(0);
        proc_group(bufB, g + 1, runL, waveM, pendR, n, ovf, wpool, lane, lmask);
    }
    if (ovf && lane == 0) s_flag = 1;   // benign race across waves

    if (lane == 0) s_red[wv] = waveReduceMax(runL);   // exact final wave max
    __syncthreads();
    const float max_val = fmaxf(fmaxf(s_red[0], s_red[1]), fmaxf(s_red[2], s_red[3]));
    const int flag = s_flag;
    __syncthreads();                     // s_red is reused below

    // v-space bounds: u = 2*tau.
    const float u_lo0 = max_val - 2.0f;
    const float u_hi  = max_val - 0.011180339887498949f;   // 2*(1/32000)^0.5

    if (!flag) {
        // ---- final eviction at thr = max-2 (block-uniform): pools shrink to
        // the true active superset (~600/row). Wave-local, deterministic. ----
        {
            int nn = 0;
            for (int i = 0; i < n; i += 64) {
                const float v = (i + lane < n) ? wpool[i + lane] : -FLT_MAX;
                const ull km = __ballot(v > u_lo0);
                const int r = __popcll(km & lmask);
                if (v > u_lo0) wpool[nn + r] = v;
                nn += __popcll(km);
            }
            if (lane == 0) s_cnt[wv] = nn;
        }
        __syncthreads();

        // ---- wave-0-only Newton solve over all 4 pools ----
        // g(u) = f(u) - 4 with f convex decreasing: tangent steps from u_lo0
        // converge monotonically from below (fp overshoot ~1 ulp). The max
        // element contributes exactly 4 at u_lo0 so g(u_lo0) >= 0; the
        // all-equal row roots exactly at u_hi, so the clamp is exact.
        if (wv == 0) {
            const int n0 = s_cnt[0], n1 = s_cnt[1], n2 = s_cnt[2], n3 = s_cnt[3];

#define POOL_SCAN2(uv, acc2, acc1)                                             \
            do {                                                               \
                const float* __restrict__ pp0 = s_pool;                        \
                for (int i = lane; i < n0; i += 64) {                          \
                    const float t = fmaxf(pp0[i] - (uv), 0.0f);                \
                    acc2 = fmaf(t, t, acc2); acc1 += t;                        \
                }                                                              \
                const float* __restrict__ pp1 = s_pool + CAPW;                 \
                for (int i = lane; i < n1; i += 64) {                          \
                    const float t = fmaxf(pp1[i] - (uv), 0.0f);                \
                    acc2 = fmaf(t, t, acc2); acc1 += t;                        \
                }                                                              \
                const float* __restrict__ pp2 = s_pool + 2 * CAPW;             \
                for (int i = lane; i < n2; i += 64) {                          \
                    const float t = fmaxf(pp2[i] - (uv), 0.0f);                \
                    acc2 = fmaf(t, t, acc2); acc1 += t;                        \
                }                                                              \
                const float* __restrict__ pp3 = s_pool + 3 * CAPW;             \
                for (int i = lane; i < n3; i += 64) {                          \
                    const float t = fmaxf(pp3[i] - (uv), 0.0f);                \
                    acc2 = fmaf(t, t, acc2); acc1 += t;                        \
                }                                                              \
            } while (0)

            float u = u_lo0;
            float s_v = 4.0f;
            for (int it = 0; it < 24; ++it) {
                float S2 = 0.0f, S1 = 0.0f;
                POOL_SCAN2(u, S2, S1);
                S2 = waveReduceSum(S2);
                S1 = waveReduceSum(S1);
                s_v = S2;                       // f at the CURRENT u
                const float g = S2 - 4.0f;
                if (g <= 0.0f) break;           // at/past root (<= 1 ulp past)
                const float u_new = fminf(u + g / (2.0f * S1), u_hi);
                if (u_new == u) break;          // fixpoint: root to fp32 precision
                u = u_new;
            }
#undef POOL_SCAN2
            if (lane == 0) { s_ts.x = u; s_ts.y = s_v; }
        }
        __syncthreads();   // solver result published
    } else {
        // ---- fallback (degenerate rows only): verified streaming bisection ----
        float u_lo = u_lo0;
        float acc = 0.0f;
        for (int k = 0; k < KITER; ++k) {
            const int c = threadIdx.x + k * NT;
            if (c < CHUNKS) {
                const float4 v = xr4[c];
                float t;
                t = fmaxf(v.x - u_lo, 0.0f); acc = fmaf(t, t, acc);
                t = fmaxf(v.y - u_lo, 0.0f); acc = fmaf(t, t, acc);
                t = fmaxf(v.z - u_lo, 0.0f); acc = fmaf(t, t, acc);
                t = fmaxf(v.w - u_lo, 0.0f); acc = fmaf(t, t, acc);
            }
        }
        acc = waveReduceSum(acc);
        if (lane == 0) s_red[wv] = acc;
        __syncthreads();
        const float f_lo = (s_red[0] + s_red[1] + s_red[2] + s_red[3]) - 4.0f;
        __syncthreads();

        float dm = u_hi - u_lo;
        float u_m = u_lo;
        float s_v = 4.0f;
        for (int it = 0; it < 100; ++it) {
            dm *= 0.5f;
            u_m = u_lo + dm;
            const bool fixed = (u_m == u_lo);
            float a = 0.0f;
            for (int k = 0; k < KITER; ++k) {
                const int c = threadIdx.x + k * NT;
                if (c < CHUNKS) {
                    const float4 v = xr4[c];
                    float t;
                    t = fmaxf(v.x - u_m, 0.0f); a = fmaf(t, t, a);
                    t = fmaxf(v.y - u_m, 0.0f); a = fmaf(t, t, a);
                    t = fmaxf(v.z - u_m, 0.0f); a = fmaf(t, t, a);
                    t = fmaxf(v.w - u_m, 0.0f); a = fmaf(t, t, a);
                }
            }
            a = waveReduceSum(a);
            if (lane == 0) s_red[wv] = a;
            __syncthreads();
            const float s = s_red[0] + s_red[1] + s_red[2] + s_red[3];
            __syncthreads();
            s_v = s;
            if ((s - 4.0f) * f_lo >= 0.0f) u_lo = u_m;
            if (fixed) break;
        }
        if (threadIdx.x == 0) { s_ts.x = u_m; s_ts.y = s_v; }
        __syncthreads();
    }

    // ---- epilogue: nt-load re-read (L3-hot, last use) -> log, nt-store ----
    // p = max(v-u,0)^2 * inv_sv is EXACTLY the z-space normalized probability.
    // Floor before log (DAZ-safe), bit-scrub residual inf/NaN.
    const float u_m = s_ts.x;
    const float inv_sv = 1.0f / s_ts.y;
    const f32x4* __restrict__ xv4 = reinterpret_cast<const f32x4*>(x + base);
    for (int k = 0; k < KITER; ++k) {
        const int c = threadIdx.x + k * NT;
        if (c < CHUNKS) {
            const f32x4 v = __builtin_nontemporal_load(xv4 + c);
            f32x4 o;
            {
                const float t = fmaxf(v.x - u_m, 0.0f);
                o.x = scrub_finite(__logf(fmaxf(t * t, 1e-35f) * inv_sv));
            }
            {
                const float t = fmaxf(v.y - u_m, 0.0f);
                o.y = scrub_finite(__logf(fmaxf(t * t, 1e-35f) * inv_sv));
            }
            {
                const float t = fmaxf(v.z - u_m, 0.0f);
                o.z = scrub_finite(__logf(fmaxf(t * t, 1e-35f) * inv_sv));
            }
            {
                const float t = fmaxf(v.w - u_m, 0.0f);
                o.w = scrub_finite(__logf(fmaxf(t * t, 1e-35f) * inv_sv));
            }
            __builtin_nontemporal_store(o, reinterpret_cast<f32x4*>(orow) + c);
        }
    }
}

extern "C" void kernel_launch(void* const* d_in, const int* in_sizes, int n_in,
                              void* d_out, int out_size, void* d_ws, size_t ws_size,
                              hipStream_t stream) {
    const float* x = (const float*)d_in[0];
    float* out = (float*)d_out;
    const int rows = in_sizes[0] / D_DIM;
    entmax_log_fused<<<dim3(rows), dim3(NT), 0, stream>>>(x, out, rows);
}

// Round 14
// 129.883 us; speedup vs baseline: 1.8529x; 1.0055x over previous
//
#include <hip/hip_runtime.h>
#include <float.h>
#include <math.h>

// Problem constants (reference: x shape (2,1024,32000) fp32, dim=-1, alpha=1.5)
// All math in v-space (v = 2z = x). 0.5 is a power of two: z = 0.5v exact,
// tau = 0.5u exact, p = max(z-tau,0)^2/sum_z == max(v-u,0)^2/sum_v (the 0.25
// cancels exactly). No scale multiply anywhere.
#define D_DIM   32000
#define NT      256                         // 4 waves -> 8 blocks/CU
#define CHUNKS  (D_DIM / 4)                 // 8000 float4 chunks per row
#define KITER   ((CHUNKS + NT - 1) / NT)    // 32 chunks per thread
#define NG4     (KITER / 4)                 // 8 four-chunk groups (16 elems each)
#define NWAVES  (NT / 64)                   // 4
#define CAPW    1200                        // per-wave pool capacity (4800 B)

typedef float f32x4 __attribute__((ext_vector_type(4)));
typedef unsigned long long ull;

__device__ __forceinline__ float waveReduceSum(float v) {
#pragma unroll
    for (int m = 32; m >= 1; m >>= 1) v += __shfl_xor(v, m, 64);
    return v;
}

__device__ __forceinline__ float waveReduceMax(float v) {
#pragma unroll
    for (int m = 32; m >= 1; m >>= 1) v = fmaxf(v, __shfl_xor(v, m, 64));
    return v;
}

// Bit-level finite scrub: maps NaN and +/-inf to -FLT_MAX. Integer-domain so
// -ffinite-math-only cannot fold it away.
__device__ __forceinline__ float scrub_finite(float v) {
    const unsigned u = __float_as_uint(v);
    if ((u & 0x7f800000u) == 0x7f800000u) return -FLT_MAX;
    return v;
}

__device__ __forceinline__ float4 ldg4(const float4* __restrict__ p, int c) {
    if (c < CHUNKS) return p[c];
    float4 r; r.x = r.y = r.z = r.w = -FLT_MAX;   // pad stays hugely negative
    return r;
}

// Fused kernel — R10 structure verbatim (verified 127.6us session best):
//  pass 1 : stream row raw. Admission thr = fmax(runL, lagWaveM) - 2 with
//           lag-pipelined wave max; ballot+rank append into per-wave LDS pool;
//           wave-cooperative eviction on overflow (entries <= thr contribute
//           exactly 0 to every f(u) at u >= max-2: eviction is exact).
//  solve  : final eviction at max-2, then wave 0 runs Newton on
//           f(u) = sum max(v-u,0)^2 (convex decreasing: monotone convergence
//           from below, ~6-8 scans vs bisection's ~25).
//  epilog : nt-load re-read (last use of x: evict-first) -> log(t^2 * inv_sv),
//           nt-store. Verified numeric path: floor before log, bit-scrub.
//           R14: guarded tail (k=31) peeled out of the epilogue loop.
__global__ __launch_bounds__(NT, 8)
void entmax_log_fused(const float* __restrict__ x, float* __restrict__ out, int rows)
{
    const int row = blockIdx.x;
    if (row >= rows) return;
    const size_t base = (size_t)row * D_DIM;
    const float4* __restrict__ xr4 = reinterpret_cast<const float4*>(x + base);
    float* __restrict__ orow = out + base;

    __shared__ __align__(16) float s_pool[NWAVES * CAPW];   // 19200 B
    __shared__ float s_red[NWAVES];
    __shared__ int   s_cnt[NWAVES];
    __shared__ int   s_flag;
    __shared__ float2 s_ts;

    const int lane = threadIdx.x & 63;
    const int wv   = threadIdx.x >> 6;
    float* __restrict__ wpool = s_pool + wv * CAPW;
    const ull lmask = (1ull << lane) - 1ull;

    if (threadIdx.x == 0) s_flag = 0;
    __syncthreads();

    // ---- pass 1: stream row; lag wave max + per-lane max admission ----
    float runL  = -FLT_MAX;   // per-lane running max (raw v)
    float waveM = -FLT_MAX;   // wave max through 2 groups ago (uniform)
    float pendR = -FLT_MAX;   // in-flight reduce result
    int n = 0;                // wave-uniform pool count
    bool ovf = false;

    float4 cur[4], nxt[4];
#pragma unroll
    for (int j = 0; j < 4; ++j) cur[j] = ldg4(xr4, threadIdx.x + j * NT);

    for (int g = 0; g < NG4; ++g) {
        if (g + 1 < NG4) {
#pragma unroll
            for (int j = 0; j < 4; ++j)
                nxt[j] = ldg4(xr4, threadIdx.x + ((g + 1) * 4 + j) * NT);
        }
        float z[16];
#pragma unroll
        for (int j = 0; j < 4; ++j) {
            z[4 * j + 0] = cur[j].x; z[4 * j + 1] = cur[j].y;
            z[4 * j + 2] = cur[j].z; z[4 * j + 3] = cur[j].w;
        }
        float cm = z[0];
#pragma unroll
        for (int i = 1; i < 16; ++i) cm = fmaxf(cm, z[i]);
        runL = fmaxf(runL, cm);
        if ((g & 1) == 0) {                   // every 8 chunks
            waveM = fmaxf(waveM, pendR);      // consume reduce from 2 groups ago
            pendR = waveReduceMax(runL);      // launch new; 2 group-times to land
        }

        float thrL = fmaxf(runL, waveM) - 2.0f;   // per-lane lower bound of max-2
        ull msk[16];
        int tot = 0;
#pragma unroll
        for (int j = 0; j < 16; ++j) {
            msk[j] = __ballot(z[j] > thrL);
            tot += __popcll(msk[j]);
        }
        if (tot) {
            if (n + tot > CAPW) {
                // fresh uniform wave max; evict dead entries (<= wfresh-2).
                const float wfresh = waveReduceMax(runL);
                waveM = fmaxf(waveM, wfresh);
                const float thrW = wfresh - 2.0f;
                int nn = 0;
                for (int i = 0; i < n; i += 64) {
                    const float v = (i + lane < n) ? wpool[i + lane] : -FLT_MAX;
                    const ull km = __ballot(v > thrW);
                    const int r = __popcll(km & lmask);
                    if (v > thrW) wpool[nn + r] = v;   // dest <= src: in-place safe
                    nn += __popcll(km);
                }
                n = nn;
                // re-admit this group against the tightened threshold
                thrL = fmaxf(runL, waveM) - 2.0f;
                tot = 0;
#pragma unroll
                for (int j = 0; j < 16; ++j) {
                    msk[j] = __ballot(z[j] > thrL);
                    tot += __popcll(msk[j]);
                }
            }
            if (n + tot > CAPW) {
                ovf = true;          // adversarial/degenerate rows only
            } else {
#pragma unroll
                for (int j = 0; j < 16; ++j) {
                    if (z[j] > thrL) {
                        const int r = __popcll(msk[j] & lmask);
                        wpool[n + r] = z[j];
                    }
                    n += __popcll(msk[j]);
                }
            }
        }
#pragma unroll
        for (int j = 0; j < 4; ++j) cur[j] = nxt[j];
    }
    if (ovf && lane == 0) s_flag = 1;   // benign race across waves

    if (lane == 0) s_red[wv] = waveReduceMax(runL);   // exact final wave max
    __syncthreads();
    const float max_val = fmaxf(fmaxf(s_red[0], s_red[1]), fmaxf(s_red[2], s_red[3]));
    const int flag = s_flag;
    __syncthreads();                     // s_red is reused below

    // v-space bounds: u = 2*tau.
    const float u_lo0 = max_val - 2.0f;
    const float u_hi  = max_val - 0.011180339887498949f;   // 2*(1/32000)^0.5

    if (!flag) {
        // ---- final eviction at thr = max-2 (block-uniform): pools shrink to
        // the true active superset (~600/row). Wave-local, deterministic. ----
        {
            int nn = 0;
            for (int i = 0; i < n; i += 64) {
                const float v = (i + lane < n) ? wpool[i + lane] : -FLT_MAX;
                const ull km = __ballot(v > u_lo0);
                const int r = __popcll(km & lmask);
                if (v > u_lo0) wpool[nn + r] = v;
                nn += __popcll(km);
            }
            if (lane == 0) s_cnt[wv] = nn;
        }
        __syncthreads();

        // ---- wave-0-only Newton solve over all 4 pools ----
        // g(u) = f(u) - 4 with f convex decreasing: tangent steps from u_lo0
        // converge monotonically from below (fp overshoot ~1 ulp). The max
        // element contributes exactly 4 at u_lo0 so g(u_lo0) >= 0; the
        // all-equal row roots exactly at u_hi, so the clamp is exact.
        if (wv == 0) {
            const int n0 = s_cnt[0], n1 = s_cnt[1], n2 = s_cnt[2], n3 = s_cnt[3];

#define POOL_SCAN2(uv, acc2, acc1)                                             \
            do {                                                               \
                const float* __restrict__ pp0 = s_pool;                        \
                for (int i = lane; i < n0; i += 64) {                          \
                    const float t = fmaxf(pp0[i] - (uv), 0.0f);                \
                    acc2 = fmaf(t, t, acc2); acc1 += t;                        \
                }                                                              \
                const float* __restrict__ pp1 = s_pool + CAPW;                 \
                for (int i = lane; i < n1; i += 64) {                          \
                    const float t = fmaxf(pp1[i] - (uv), 0.0f);                \
                    acc2 = fmaf(t, t, acc2); acc1 += t;                        \
                }                                                              \
                const float* __restrict__ pp2 = s_pool + 2 * CAPW;             \
                for (int i = lane; i < n2; i += 64) {                          \
                    const float t = fmaxf(pp2[i] - (uv), 0.0f);                \
                    acc2 = fmaf(t, t, acc2); acc1 += t;                        \
                }                                                              \
                const float* __restrict__ pp3 = s_pool + 3 * CAPW;             \
                for (int i = lane; i < n3; i += 64) {                          \
                    const float t = fmaxf(pp3[i] - (uv), 0.0f);                \
                    acc2 = fmaf(t, t, acc2); acc1 += t;                        \
                }                                                              \
            } while (0)

            float u = u_lo0;
            float s_v = 4.0f;
            for (int it = 0; it < 24; ++it) {
                float S2 = 0.0f, S1 = 0.0f;
                POOL_SCAN2(u, S2, S1);
                S2 = waveReduceSum(S2);
                S1 = waveReduceSum(S1);
                s_v = S2;                       // f at the CURRENT u
                const float g = S2 - 4.0f;
                if (g <= 0.0f) break;           // at/past root (<= 1 ulp past)
                const float u_new = fminf(u + g / (2.0f * S1), u_hi);
                if (u_new == u) break;          // fixpoint: root to fp32 precision
                u = u_new;
            }
#undef POOL_SCAN2
            if (lane == 0) { s_ts.x = u; s_ts.y = s_v; }
        }
        __syncthreads();   // solver result published
    } else {
        // ---- fallback (degenerate rows only): verified streaming bisection ----
        float u_lo = u_lo0;
        float acc = 0.0f;
        for (int k = 0; k < KITER; ++k) {
            const int c = threadIdx.x + k * NT;
            if (c < CHUNKS) {
                const float4 v = xr4[c];
                float t;
                t = fmaxf(v.x - u_lo, 0.0f); acc = fmaf(t, t, acc);
                t = fmaxf(v.y - u_lo, 0.0f); acc = fmaf(t, t, acc);
                t = fmaxf(v.z - u_lo, 0.0f); acc = fmaf(t, t, acc);
                t = fmaxf(v.w - u_lo, 0.0f); acc = fmaf(t, t, acc);
            }
        }
        acc = waveReduceSum(acc);
        if (lane == 0) s_red[wv] = acc;
        __syncthreads();
        const float f_lo = (s_red[0] + s_red[1] + s_red[2] + s_red[3]) - 4.0f;
        __syncthreads();

        float dm = u_hi - u_lo;
        float u_m = u_lo;
        float s_v = 4.0f;
        for (int it = 0; it < 100; ++it) {
            dm *= 0.5f;
            u_m = u_lo + dm;
            const bool fixed = (u_m == u_lo);
            float a = 0.0f;
            for (int k = 0; k < KITER; ++k) {
                const int c = threadIdx.x + k * NT;
                if (c < CHUNKS) {
                    const float4 v = xr4[c];
                    float t;
                    t = fmaxf(v.x - u_m, 0.0f); a = fmaf(t, t, a);
                    t = fmaxf(v.y - u_m, 0.0f); a = fmaf(t, t, a);
                    t = fmaxf(v.z - u_m, 0.0f); a = fmaf(t, t, a);
                    t = fmaxf(v.w - u_m, 0.0f); a = fmaf(t, t, a);
                }
            }
            a = waveReduceSum(a);
            if (lane == 0) s_red[wv] = a;
            __syncthreads();
            const float s = s_red[0] + s_red[1] + s_red[2] + s_red[3];
            __syncthreads();
            s_v = s;
            if ((s - 4.0f) * f_lo >= 0.0f) u_lo = u_m;
            if (fixed) break;
        }
        if (threadIdx.x == 0) { s_ts.x = u_m; s_ts.y = s_v; }
        __syncthreads();
    }

    // ---- epilogue: nt-load re-read (L3-hot, last use) -> log, nt-store ----
    // p = max(v-u,0)^2 * inv_sv is EXACTLY the z-space normalized probability.
    // Floor before log (DAZ-safe), bit-scrub residual inf/NaN.
    // Tail peeled: k = 0..30 are always fully in-bounds (tid + 30*256 < 8000).
    const float u_m = s_ts.x;
    const float inv_sv = 1.0f / s_ts.y;
    const f32x4* __restrict__ xv4 = reinterpret_cast<const f32x4*>(x + base);

#define EPI_CHUNK(c)                                                           \
    do {                                                                       \
        const f32x4 v = __builtin_nontemporal_load(xv4 + (c));                 \
        f32x4 o;                                                               \
        {                                                                      \
            const float t = fmaxf(v.x - u_m, 0.0f);                            \
            o.x = scrub_finite(__logf(fmaxf(t * t, 1e-35f) * inv_sv));         \
        }                                                                      \
        {                                                                      \
            const float t = fmaxf(v.y - u_m, 0.0f);                            \
            o.y = scrub_finite(__logf(fmaxf(t * t, 1e-35f) * inv_sv));         \
        }                                                                      \
        {                                                                      \
            const float t = fmaxf(v.z - u_m, 0.0f);                            \
            o.z = scrub_finite(__logf(fmaxf(t * t, 1e-35f) * inv_sv));         \
        }                                                                      \
        {                                                                      \
            const float t = fmaxf(v.w - u_m, 0.0f);                            \
            o.w = scrub_finite(__logf(fmaxf(t * t, 1e-35f) * inv_sv));         \
        }                                                                      \
        __builtin_nontemporal_store(o, reinterpret_cast<f32x4*>(orow) + (c));  \
    } while (0)

    for (int k = 0; k < KITER - 1; ++k) {          // always in-bounds
        EPI_CHUNK(threadIdx.x + k * NT);
    }
    {                                              // peeled guarded tail
        const int c = threadIdx.x + (KITER - 1) * NT;
        if (c < CHUNKS) EPI_CHUNK(c);
    }
#undef EPI_CHUNK
}

extern "C" void kernel_launch(void* const* d_in, const int* in_sizes, int n_in,
                              void* d_out, int out_size, void* d_ws, size_t ws_size,
                              hipStream_t stream) {
    const float* x = (const float*)d_in[0];
    float* out = (float*)d_out;
    const int rows = in_sizes[0] / D_DIM;
    entmax_log_fused<<<dim3(rows), dim3(NT), 0, stream>>>(x, out, rows);
}